// Round 1
// baseline (8080.430 us; speedup 1.0000x reference)
//
#include <hip/hip_runtime.h>

#define NB 64
#define NS 256
#define NH 1024
#define NE 512
#define NV 10000
#define NT 64
#define ND 512
#define NEH 1536
#define NG 4096   // 2 dirs * 4*D gate width

// ---------------------------------------------------------------------------
// Generic 64x64 fp32 tile:  C[m,n] = sum_k A[m*lda+k] * W[n*ldw+k]
// ---------------------------------------------------------------------------
__device__ __forceinline__ void tile64(
    const float* __restrict__ A, int lda,
    const float* __restrict__ W, int ldw,
    float* __restrict__ C, int ldc,
    int Kc, int nvalid,
    float (*As)[64], float (*Ws)[64])
{
  const int tid = threadIdx.x;
  const int lr = tid >> 2;          // 0..63 row within tile
  const int lc = (tid & 3) << 2;    // 0,4,8,12 k offset
  const int tx = tid & 15, ty = tid >> 4;
  float acc[4][4] = {{0.f}};
  const bool wok = lr < nvalid;
  for (int kt = 0; kt < Kc; kt += 16) {
    float4 av = *(const float4*)(A + (size_t)lr * lda + kt + lc);
    float4 wv = make_float4(0.f, 0.f, 0.f, 0.f);
    if (wok) wv = *(const float4*)(W + (size_t)lr * ldw + kt + lc);
    As[lc + 0][lr] = av.x; As[lc + 1][lr] = av.y;
    As[lc + 2][lr] = av.z; As[lc + 3][lr] = av.w;
    Ws[lc + 0][lr] = wv.x; Ws[lc + 1][lr] = wv.y;
    Ws[lc + 2][lr] = wv.z; Ws[lc + 3][lr] = wv.w;
    __syncthreads();
#pragma unroll
    for (int kk = 0; kk < 16; ++kk) {
      float4 a = *(const float4*)(&As[kk][ty << 2]);
      float4 b = *(const float4*)(&Ws[kk][tx << 2]);
      acc[0][0] += a.x * b.x; acc[0][1] += a.x * b.y; acc[0][2] += a.x * b.z; acc[0][3] += a.x * b.w;
      acc[1][0] += a.y * b.x; acc[1][1] += a.y * b.y; acc[1][2] += a.y * b.z; acc[1][3] += a.y * b.w;
      acc[2][0] += a.z * b.x; acc[2][1] += a.z * b.y; acc[2][2] += a.z * b.z; acc[2][3] += a.z * b.w;
      acc[3][0] += a.w * b.x; acc[3][1] += a.w * b.y; acc[3][2] += a.w * b.z; acc[3][3] += a.w * b.w;
    }
    __syncthreads();
  }
#pragma unroll
  for (int i = 0; i < 4; ++i) {
    const int cm = (ty << 2) + i;
#pragma unroll
    for (int j = 0; j < 4; ++j) {
      const int cn = (tx << 2) + j;
      if (cn < nvalid) C[(size_t)cm * ldc + cn] = acc[i][j];
    }
  }
}

// grid: (ceil(N/64), Mtot/64, SK). Writes partials C[z][Mtot][N].
__global__ __launch_bounds__(256) void gemm_part(
    const float* __restrict__ A, int lda,
    const float* __restrict__ W, int ldw,
    float* __restrict__ C, int Mtot, int N, int Kc)
{
  __shared__ float As[16][64];
  __shared__ float Ws[16][64];
  const int m0 = blockIdx.y * 64;
  const int n0 = blockIdx.x * 64;
  const int k0 = blockIdx.z * Kc;
  const float* Ap = A + (size_t)m0 * lda + k0;
  const float* Wp = W + (size_t)n0 * ldw + k0;
  float* Cp = C + (size_t)blockIdx.z * Mtot * N + (size_t)m0 * N + n0;
  tile64(Ap, lda, Wp, ldw, Cp, N, Kc, N - n0, As, Ws);
}

// Fused LSTM gates GEMM: g[b, dir*2048 + j] = x@Wih_dir^T + h_dir@Whh_dir^T
// grid (64, 1, 8): combined K = 1536 (x) + 512 (h), chunks of 256.
__global__ __launch_bounds__(256) void gates_gemm(
    const float* __restrict__ x,    // [B][1536]
    const float* __restrict__ hq,   // [B][H]
    const float* __restrict__ Wih_f, const float* __restrict__ Whh_f,
    const float* __restrict__ Wih_b, const float* __restrict__ Whh_b,
    float* __restrict__ gp)         // [8][B][4096]
{
  __shared__ float As[16][64];
  __shared__ float Ws[16][64];
  const int n0 = blockIdx.x * 64;
  const int dir = n0 >> 11;
  const int j0 = n0 & 2047;
  const int z = blockIdx.z;
  const float* A; int lda; const float* W; int ldw;
  if (z < 6) {
    A = x + z * 256; lda = NEH;
    W = (dir ? Wih_b : Wih_f) + (size_t)j0 * NEH + z * 256; ldw = NEH;
  } else {
    A = hq + dir * ND + (z - 6) * 256; lda = NH;
    W = (dir ? Whh_b : Whh_f) + (size_t)j0 * ND + (z - 6) * 256; ldw = ND;
  }
  float* C = gp + (size_t)z * NB * NG + n0;
  tile64(A, lda, W, ldw, C, NG, 256, 64, As, Ws);
}

// ---------------------------------------------------------------------------
__global__ __launch_bounds__(256) void init_state(
    const float* __restrict__ h0, const float* __restrict__ c0,
    float* __restrict__ hq, float* __restrict__ cq)
{
  int idx = blockIdx.x * 256 + threadIdx.x;   // b*H + dir*D + d
  int b = idx >> 10, dir = (idx >> 9) & 1, d = idx & 511;
  int src = dir * NB * ND + b * ND + d;
  hq[idx] = h0[src];
  cq[idx] = c0[src];
}

__global__ __launch_bounds__(256) void final_state(
    const float* __restrict__ hq, const float* __restrict__ cq,
    float* __restrict__ out_h, float* __restrict__ out_c)
{
  int idx = blockIdx.x * 256 + threadIdx.x;   // dir*B*D + b*D + d
  int dir = idx >> 15, r = idx & 32767, b = r >> 9, d = r & 511;
  int src = b * NH + dir * ND + d;
  out_h[idx] = hq[src];
  out_c[idx] = cq[src];
}

__global__ __launch_bounds__(256) void reduce_q(
    const float* __restrict__ qp, float* __restrict__ q)
{
  int idx = blockIdx.x * 256 + threadIdx.x;   // B*H
  float a = 0.f;
#pragma unroll
  for (int z = 0; z < 8; ++z) a += qp[(size_t)z * NB * NH + idx];
  q[idx] = a;
}

// sc[b,s] = sum_h Va[h] * tanh(q[b,h] + Uk[b,s,h]);  grid B*S blocks
__global__ __launch_bounds__(256) void attn_score(
    const float* __restrict__ q, const float* __restrict__ Uk,
    const float* __restrict__ Va, const unsigned char* __restrict__ mask,
    float* __restrict__ sc)
{
  const int bs = blockIdx.x;
  const int b = bs >> 8;
  const float* ukp = Uk + (size_t)bs * NH;
  const float* qp = q + b * NH;
  const int tid = threadIdx.x;
  float acc = 0.f;
#pragma unroll
  for (int h = tid; h < NH; h += 256)
    acc += Va[h] * tanhf(qp[h] + ukp[h]);
#pragma unroll
  for (int off = 32; off; off >>= 1) acc += __shfl_down(acc, off);
  __shared__ float red[4];
  if ((tid & 63) == 0) red[tid >> 6] = acc;
  __syncthreads();
  if (tid == 0) {
    float s = red[0] + red[1] + red[2] + red[3];
    sc[bs] = mask[bs] ? -__builtin_inff() : s;
  }
}

// in-place softmax over S; also writes attentions output. grid B, block S=256
__global__ __launch_bounds__(256) void softmax_w(
    float* __restrict__ w, float* __restrict__ attn_out, int t)
{
  const int b = blockIdx.x;
  const int s = threadIdx.x;
  float v = w[b * NS + s];
  float m = v;
#pragma unroll
  for (int off = 32; off; off >>= 1) m = fmaxf(m, __shfl_down(m, off));
  __shared__ float red[4];
  __shared__ float bm, bsum;
  if ((s & 63) == 0) red[s >> 6] = m;
  __syncthreads();
  if (s == 0) bm = fmaxf(fmaxf(red[0], red[1]), fmaxf(red[2], red[3]));
  __syncthreads();
  float e = __expf(v - bm);
  float su = e;
#pragma unroll
  for (int off = 32; off; off >>= 1) su += __shfl_down(su, off);
  if ((s & 63) == 0) red[s >> 6] = su;
  __syncthreads();
  if (s == 0) bsum = red[0] + red[1] + red[2] + red[3];
  __syncthreads();
  float ww = e / bsum;
  w[b * NS + s] = ww;
  attn_out[((size_t)b * NT + t) * NS + s] = ww;
}

// blocks 0..255: ctx -> x[:, E:E+H]; blocks 256..383: emb[tok] -> x[:, 0:E]
__global__ __launch_bounds__(256) void ctx_emb(
    const float* __restrict__ w, const float* __restrict__ enc,
    const float* __restrict__ emb, const int* __restrict__ target,
    const int* __restrict__ sos, float* __restrict__ x, int t)
{
  const int blk = blockIdx.x;
  if (blk < 256) {
    const int b = blk >> 2;
    const int h = ((blk & 3) << 8) + threadIdx.x;
    __shared__ float ws[NS];
    ws[threadIdx.x] = w[b * NS + threadIdx.x];
    __syncthreads();
    const float* ep = enc + (size_t)b * NS * NH + h;
    float acc = 0.f;
#pragma unroll 4
    for (int s = 0; s < NS; ++s) acc += ws[s] * ep[(size_t)s * NH];
    x[b * NEH + NE + h] = acc;
  } else {
    const int idx = (blk - 256) * 256 + threadIdx.x;   // [0, B*E)
    const int b = idx >> 9;
    const int e = idx & 511;
    const int tok = (t == 0) ? sos[0] : target[b * NT + t - 1];
    x[b * NEH + e] = emb[(size_t)tok * NE + e];
  }
}

// reduce 8 gate partials + biases, apply LSTM cell. grid 2*B*D/256
__global__ __launch_bounds__(256) void gate_elt(
    const float* __restrict__ gp,
    const float* __restrict__ bih_f, const float* __restrict__ bhh_f,
    const float* __restrict__ bih_b, const float* __restrict__ bhh_b,
    const float* __restrict__ cq_old,
    float* __restrict__ hq_new, float* __restrict__ cq_new)
{
  const int idx = blockIdx.x * 256 + threadIdx.x;   // b*H + dir*D + d
  const int b = idx >> 10, dir = (idx >> 9) & 1, d = idx & 511;
  const float* bih = dir ? bih_b : bih_f;
  const float* bhh = dir ? bhh_b : bhh_f;
  const size_t gbase = (size_t)b * NG + (dir << 11);
  float gi = bih[d] + bhh[d];
  float gf = bih[512 + d] + bhh[512 + d];
  float gg = bih[1024 + d] + bhh[1024 + d];
  float go = bih[1536 + d] + bhh[1536 + d];
#pragma unroll
  for (int z = 0; z < 8; ++z) {
    const float* g = gp + (size_t)z * NB * NG + gbase;
    gi += g[d]; gf += g[512 + d]; gg += g[1024 + d]; go += g[1536 + d];
  }
  const float c0 = cq_old[idx];
  const float si = 1.f / (1.f + __expf(-gi));
  const float sf = 1.f / (1.f + __expf(-gf));
  const float so = 1.f / (1.f + __expf(-go));
  const float tg = tanhf(gg);
  const float c2 = sf * c0 + si * tg;
  const float h2 = so * tanhf(c2);
  hq_new[idx] = h2;
  cq_new[idx] = c2;
}

// decoder_outputs[b,t,:] = sum_z lp[z][b][:] + out_b. grid B*V/256
__global__ __launch_bounds__(256) void logits_out(
    const float* __restrict__ lp, const float* __restrict__ out_b,
    float* __restrict__ dec, int t)
{
  const int idx = blockIdx.x * 256 + threadIdx.x;   // [0, B*V)
  const int b = idx / NV;
  const int v = idx - b * NV;
  float acc = out_b[v];
#pragma unroll
  for (int z = 0; z < 4; ++z) acc += lp[(size_t)z * NB * NV + idx];
  dec[((size_t)b * NT + t) * NV + v] = acc;
}

// ---------------------------------------------------------------------------
extern "C" void kernel_launch(void* const* d_in, const int* in_sizes, int n_in,
                              void* d_out, int out_size, void* d_ws, size_t ws_size,
                              hipStream_t stream)
{
  const float* enc    = (const float*)d_in[0];
  const float* h0     = (const float*)d_in[1];
  const float* c0     = (const float*)d_in[2];
  const int*   target = (const int*)d_in[3];
  const unsigned char* mask = (const unsigned char*)d_in[4];
  const int*   sos    = (const int*)d_in[5];
  const float* emb    = (const float*)d_in[6];
  const float* Wa     = (const float*)d_in[7];
  const float* Ua     = (const float*)d_in[8];
  const float* Va     = (const float*)d_in[9];
  const float* out_W  = (const float*)d_in[10];
  const float* out_b  = (const float*)d_in[11];
  const float* Wih_f  = (const float*)d_in[12];
  const float* Whh_f  = (const float*)d_in[13];
  const float* bih_f  = (const float*)d_in[14];
  const float* bhh_f  = (const float*)d_in[15];
  const float* Wih_b  = (const float*)d_in[16];
  const float* Whh_b  = (const float*)d_in[17];
  const float* bih_b  = (const float*)d_in[18];
  const float* bhh_b  = (const float*)d_in[19];

  float* out_dec  = (float*)d_out;                       // [B][T][V]
  float* out_h    = out_dec + (size_t)NB * NT * NV;      // [2][B][D]
  float* out_c    = out_h + 2 * NB * ND;                 // [2][B][D]
  float* out_attn = out_c + 2 * NB * ND;                 // [B][T][S]

  float* w0 = (float*)d_ws;
  size_t off = 0;
  float* Uk  = w0 + off; off += (size_t)NB * NS * NH;    // 16,777,216
  float* qp  = w0 + off; off += 8 * (size_t)NB * NH;     // partials for q
  float* q   = w0 + off; off += (size_t)NB * NH;
  float* wat = w0 + off; off += (size_t)NB * NS;         // sc then w (in place)
  float* x   = w0 + off; off += (size_t)NB * NEH;
  float* gp  = w0 + off; off += 8 * (size_t)NB * NG;
  float* lp  = w0 + off; off += 4 * (size_t)NB * NV;
  float* hq  = w0 + off; off += 2 * (size_t)NB * NH;
  float* cq  = w0 + off; off += 2 * (size_t)NB * NH;
  if (ws_size < off * sizeof(float)) return;   // insufficient scratch

  init_state<<<dim3(256), dim3(256), 0, stream>>>(h0, c0, hq, cq);

  // Uk[b,s,k] = sum_h enc[b,s,h] * Ua[k,h]   (one-time)
  gemm_part<<<dim3(16, 256, 1), dim3(256), 0, stream>>>(enc, NH, Ua, NH, Uk,
                                                        NB * NS, NH, NH);

  for (int t = 0; t < NT; ++t) {
    float* hq_cur = hq + (t & 1) * (NB * NH);
    float* hq_nxt = hq + ((t & 1) ^ 1) * (NB * NH);
    float* cq_cur = cq + (t & 1) * (NB * NH);
    float* cq_nxt = cq + ((t & 1) ^ 1) * (NB * NH);

    // q = query @ Wa^T   (split-K 8)
    gemm_part<<<dim3(16, 1, 8), dim3(256), 0, stream>>>(hq_cur, NH, Wa, NH, qp,
                                                        NB, NH, 128);
    reduce_q<<<dim3(256), dim3(256), 0, stream>>>(qp, q);

    attn_score<<<dim3(NB * NS), dim3(256), 0, stream>>>(q, Uk, Va, mask, wat);
    softmax_w<<<dim3(NB), dim3(256), 0, stream>>>(wat, out_attn, t);
    ctx_emb<<<dim3(384), dim3(256), 0, stream>>>(wat, enc, emb, target, sos, x, t);

    gates_gemm<<<dim3(64, 1, 8), dim3(256), 0, stream>>>(x, hq_cur, Wih_f, Whh_f,
                                                         Wih_b, Whh_b, gp);
    gate_elt<<<dim3(256), dim3(256), 0, stream>>>(gp, bih_f, bhh_f, bih_b, bhh_b,
                                                  cq_cur, hq_nxt, cq_nxt);

    // logits = out @ out_W^T + out_b  (split-K 4)
    gemm_part<<<dim3(157, 1, 4), dim3(256), 0, stream>>>(hq_nxt, NH, out_W, NH, lp,
                                                         NB, NV, 256);
    logits_out<<<dim3(2500), dim3(256), 0, stream>>>(lp, out_b, out_dec, t);
  }

  // after t=63, new state lives in buffer 0
  final_state<<<dim3(256), dim3(256), 0, stream>>>(hq, cq, out_h, out_c);
}

// Round 2
// 4076.260 us; speedup vs baseline: 1.9823x; 1.9823x over previous
//
#include <hip/hip_runtime.h>

#define NB 64
#define NS 256
#define NH 1024
#define NE 512
#define NV 10000
#define NT 64
#define ND 512
#define NEH 1536
#define NG 4096

typedef __attribute__((ext_vector_type(8))) short bf16x8;
typedef __attribute__((ext_vector_type(4))) float f32x4;

__device__ __forceinline__ short F2B(float f) {
  unsigned u = __float_as_uint(f);
  return (short)((u + 0x7fffu + ((u >> 16) & 1u)) >> 16);
}
__device__ __forceinline__ float B2F(short s) {
  return __uint_as_float(((unsigned)(unsigned short)s) << 16);
}
__device__ __forceinline__ float ftanh(float x) {
  float e = __expf(2.f * x);                       // inf for big x -> rcp=0 -> 1
  return 1.f - 2.f * __builtin_amdgcn_rcpf(e + 1.f);
}

#define GLD16(src, dst)                                                        \
  __builtin_amdgcn_global_load_lds(                                            \
      (const __attribute__((address_space(1))) void*)(src),                    \
      (__attribute__((address_space(3))) void*)(dst), 16, 0, 0)

// ---------------------------------------------------------------------------
// C[m,n] = sum_k A[m,k]*W[n,k], M=64 tile, N=64 tile, bf16 inputs, BK=64.
// XOR-swizzled LDS: tile [64 rows][8 chunks of 16B], phys chunk = c ^ (row&7).
// AF32: A is fp32, staged with on-the-fly convert (used once, for Uk).
// nlim: valid cols at this tile (W rows clamped, col writes guarded).
// ---------------------------------------------------------------------------
template <bool AF32>
__device__ __forceinline__ void mm64_core(
    const void* Av, int lda, const short* __restrict__ Wg, int ldw, int K,
    int nlim, float* Cf, short* Ch, size_t ldc, const float* bias, char* smem)
{
  short* As = (short*)smem;
  short* Bs = (short*)(smem + 8192);
  const int tid = threadIdx.x;
  const int lane = tid & 63, w = tid >> 6;
  const int qm = (w >> 1) << 5, qn = (w & 1) << 5;
  const int kg = lane >> 4, rl = lane & 15;
  f32x4 acc[2][2] = {};

  for (int k0 = 0; k0 < K; k0 += 64) {
    if (AF32) {
      const float* Af = (const float*)Av;
#pragma unroll
      for (int p = 0; p < 2; ++p) {
        int j = tid + (p << 8);
        int row = j >> 3;
        int c = (j & 7) ^ (row & 7);
        const float* src = Af + (size_t)row * lda + k0 + (c << 3);
        float4 v0 = ((const float4*)src)[0];
        float4 v1 = ((const float4*)src)[1];
        bf16x8 pk;
        pk[0] = F2B(v0.x); pk[1] = F2B(v0.y); pk[2] = F2B(v0.z); pk[3] = F2B(v0.w);
        pk[4] = F2B(v1.x); pk[5] = F2B(v1.y); pk[6] = F2B(v1.z); pk[7] = F2B(v1.w);
        *((bf16x8*)As + j) = pk;
      }
    } else {
      const short* Ab = (const short*)Av;
#pragma unroll
      for (int p = 0; p < 2; ++p) {
        int j = (w << 7) + (p << 6) + lane;
        int row = j >> 3;
        int c = (j & 7) ^ (row & 7);
        GLD16(Ab + (size_t)row * lda + k0 + (c << 3),
              smem + (w << 11) + (p << 10));
      }
    }
#pragma unroll
    for (int p = 0; p < 2; ++p) {
      int j = (w << 7) + (p << 6) + lane;
      int row = j >> 3;
      int wr = min(row, nlim - 1);
      int c = (j & 7) ^ (row & 7);
      GLD16(Wg + (size_t)wr * ldw + k0 + (c << 3),
            smem + 8192 + (w << 11) + (p << 10));
    }
    __syncthreads();
#pragma unroll
    for (int kk = 0; kk < 2; ++kk) {
      bf16x8 af[2], bfr[2];
#pragma unroll
      for (int mt = 0; mt < 2; ++mt) {
        int row = qm + (mt << 4) + rl;
        int c = (kk << 2) + kg;
        af[mt] = *((const bf16x8*)As + ((row << 3) | (c ^ (row & 7))));
      }
#pragma unroll
      for (int nt = 0; nt < 2; ++nt) {
        int row = qn + (nt << 4) + rl;
        int c = (kk << 2) + kg;
        bfr[nt] = *((const bf16x8*)Bs + ((row << 3) | (c ^ (row & 7))));
      }
#pragma unroll
      for (int mt = 0; mt < 2; ++mt)
#pragma unroll
        for (int nt = 0; nt < 2; ++nt)
          acc[mt][nt] = __builtin_amdgcn_mfma_f32_16x16x32_bf16(
              af[mt], bfr[nt], acc[mt][nt], 0, 0, 0);
    }
    __syncthreads();
  }

#pragma unroll
  for (int mt = 0; mt < 2; ++mt) {
#pragma unroll
    for (int nt = 0; nt < 2; ++nt) {
      int cn = qn + (nt << 4) + rl;
      if (cn < nlim) {
        float bv = bias ? bias[cn] : 0.f;
#pragma unroll
        for (int r = 0; r < 4; ++r) {
          int rowm = qm + (mt << 4) + (kg << 2) + r;
          float v = acc[mt][nt][r] + bv;
          if (Cf) Cf[(size_t)rowm * ldc + cn] = v;
          else Ch[(size_t)rowm * ldc + cn] = F2B(v);
        }
      }
    }
  }
}

// --- GEMM kernel wrappers ---------------------------------------------------
__global__ __launch_bounds__(256) void uk_mm(const float* __restrict__ enc,
                                             const short* __restrict__ Ua_h,
                                             short* __restrict__ Uk_h) {
  __shared__ char smem[16384];
  mm64_core<true>(enc + (size_t)blockIdx.y * 64 * NH, NH,
                  Ua_h + (size_t)blockIdx.x * 64 * NH, NH, NH, 64,
                  nullptr, Uk_h + (size_t)blockIdx.y * 64 * NH + blockIdx.x * 64,
                  NH, nullptr, smem);
}

__global__ __launch_bounds__(256) void q_mm(const short* __restrict__ hqh,
                                            const short* __restrict__ Wa_h,
                                            float* __restrict__ q) {
  __shared__ char smem[16384];
  mm64_core<false>(hqh, NH, Wa_h + (size_t)blockIdx.x * 64 * NH, NH, NH, 64,
                   q + blockIdx.x * 64, nullptr, NH, nullptr, smem);
}

__global__ __launch_bounds__(256) void gates_mm(
    const short* __restrict__ x_h, const short* __restrict__ hqh,
    const short* __restrict__ Wif, const short* __restrict__ Whf,
    const short* __restrict__ Wib, const short* __restrict__ Whb,
    float* __restrict__ gp) {
  __shared__ char smem[16384];
  const int n0 = blockIdx.x * 64, z = blockIdx.z;
  const int dir = n0 >> 11, j0 = n0 & 2047;
  const short* A; int lda; const short* W; int ldw;
  if (z < 3) {
    A = x_h + z * 512; lda = NEH;
    W = (dir ? Wib : Wif) + (size_t)j0 * NEH + z * 512; ldw = NEH;
  } else {
    A = hqh + dir * 512; lda = NH;
    W = (dir ? Whb : Whf) + (size_t)j0 * 512; ldw = 512;
  }
  mm64_core<false>(A, lda, W, ldw, 512, 64,
                   gp + (size_t)z * NB * NG + n0, nullptr, NG, nullptr, smem);
}

__global__ __launch_bounds__(256) void logits_mm(
    const short* __restrict__ hqh, const short* __restrict__ ow_h,
    const float* __restrict__ out_b, float* __restrict__ dec, int t) {
  __shared__ char smem[16384];
  const int n0 = blockIdx.x * 64;
  const int nlim = min(64, NV - n0);
  mm64_core<false>(hqh, NH, ow_h + (size_t)n0 * NH, NH, NH, nlim,
                   dec + (size_t)t * NV + n0, nullptr, (size_t)NT * NV,
                   out_b + n0, smem);
}

// --- small kernels ----------------------------------------------------------
__global__ __launch_bounds__(256) void f2b_k(const float* __restrict__ in,
                                             short* __restrict__ out, int n4) {
  int i = blockIdx.x * 256 + threadIdx.x;
  const int stride = gridDim.x * 256;
  for (; i < n4; i += stride) {
    float4 v = ((const float4*)in)[i];
    short4 o;
    o.x = F2B(v.x); o.y = F2B(v.y); o.z = F2B(v.z); o.w = F2B(v.w);
    ((short4*)out)[i] = o;
  }
}

__global__ __launch_bounds__(256) void init_state(
    const float* __restrict__ h0, const float* __restrict__ c0,
    float* __restrict__ hq, float* __restrict__ cq, short* __restrict__ hqh) {
  int idx = blockIdx.x * 256 + threadIdx.x;
  int b = idx >> 10, dir = (idx >> 9) & 1, d = idx & 511;
  int src = dir * NB * ND + b * ND + d;
  float h = h0[src];
  hq[idx] = h;
  hqh[idx] = F2B(h);
  cq[idx] = c0[src];
}

__global__ __launch_bounds__(256) void final_state(
    const float* __restrict__ hq, const float* __restrict__ cq,
    float* __restrict__ out_h, float* __restrict__ out_c) {
  int idx = blockIdx.x * 256 + threadIdx.x;
  int dir = idx >> 15, r = idx & 32767, b = r >> 9, d = r & 511;
  int src = b * NH + dir * ND + d;
  out_h[idx] = hq[src];
  out_c[idx] = cq[src];
}

// one wave per (b,s): sc[b,s] = mask ? -inf : sum_h Va[h]*tanh(q[b,h]+Uk[b,s,h])
__global__ __launch_bounds__(256) void attn_score(
    const float* __restrict__ q, const short* __restrict__ Uk,
    const float* __restrict__ Va, const unsigned char* __restrict__ mask,
    float* __restrict__ sc) {
  const int lane = threadIdx.x & 63, wid = threadIdx.x >> 6;
  const int bs = blockIdx.x * 4 + wid;
  const int b = bs >> 8;
  const short* ukp = Uk + (size_t)bs * NH;
  const float* qp = q + (size_t)b * NH;
  float acc = 0.f;
#pragma unroll
  for (int i = 0; i < 4; ++i) {
    int h = i * 256 + (lane << 2);
    short4 uv = *(const short4*)(ukp + h);
    float4 qv = *(const float4*)(qp + h);
    float4 vv = *(const float4*)(Va + h);
    acc += vv.x * ftanh(qv.x + B2F(uv.x));
    acc += vv.y * ftanh(qv.y + B2F(uv.y));
    acc += vv.z * ftanh(qv.z + B2F(uv.z));
    acc += vv.w * ftanh(qv.w + B2F(uv.w));
  }
#pragma unroll
  for (int o = 32; o; o >>= 1) acc += __shfl_down(acc, o);
  if (lane == 0) sc[bs] = mask[bs] ? -__builtin_inff() : acc;
}

// blocks 0..255: (b, h-quarter): local softmax over sc[b,:] + ctx -> x_h[:,E:]
// blocks 256..383: emb gather -> x_h[:,0:E]
__global__ __launch_bounds__(256) void ctx_soft(
    const float* __restrict__ sc, const float* __restrict__ enc_f,
    const short* __restrict__ enc_h, int use_h, const float* __restrict__ emb,
    const int* __restrict__ target, const int* __restrict__ sos,
    short* __restrict__ x_h, float* __restrict__ attn_out, int t) {
  const int blk = blockIdx.x, tid = threadIdx.x;
  if (blk < 256) {
    const int b = blk >> 2, qh = blk & 3;
    __shared__ float red[4];
    __shared__ float ws[NS];
    float v = sc[b * NS + tid];
    float m = v;
#pragma unroll
    for (int o = 32; o; o >>= 1) m = fmaxf(m, __shfl_down(m, o));
    if ((tid & 63) == 0) red[tid >> 6] = m;
    __syncthreads();
    m = fmaxf(fmaxf(red[0], red[1]), fmaxf(red[2], red[3]));
    float e = __expf(v - m);
    float su = e;
#pragma unroll
    for (int o = 32; o; o >>= 1) su += __shfl_down(su, o);
    __syncthreads();
    if ((tid & 63) == 0) red[tid >> 6] = su;
    __syncthreads();
    su = red[0] + red[1] + red[2] + red[3];
    float wgt = e / su;
    ws[tid] = wgt;
    if (qh == 0) attn_out[((size_t)b * NT + t) * NS + tid] = wgt;
    __syncthreads();
    const int h = (qh << 8) + tid;
    float acc = 0.f;
    if (use_h) {
      const short* ep = enc_h + (size_t)b * NS * NH + h;
#pragma unroll 4
      for (int s = 0; s < NS; ++s) acc += ws[s] * B2F(ep[(size_t)s * NH]);
    } else {
      const float* ep = enc_f + (size_t)b * NS * NH + h;
#pragma unroll 4
      for (int s = 0; s < NS; ++s) acc += ws[s] * ep[(size_t)s * NH];
    }
    x_h[b * NEH + NE + h] = F2B(acc);
  } else {
    const int idx = (blk - 256) * 256 + tid;
    const int b = idx >> 9, e = idx & 511;
    const int tok = (t == 0) ? sos[0] : target[b * NT + t - 1];
    x_h[b * NEH + e] = F2B(emb[(size_t)tok * NE + e]);
  }
}

__global__ __launch_bounds__(256) void gate_elt(
    const float* __restrict__ gp, const float* __restrict__ bih_f,
    const float* __restrict__ bhh_f, const float* __restrict__ bih_b,
    const float* __restrict__ bhh_b, const float* __restrict__ cq_old,
    float* __restrict__ hq_new, float* __restrict__ cq_new,
    short* __restrict__ hqh_new) {
  const int idx = blockIdx.x * 256 + threadIdx.x;
  const int b = idx >> 10, dir = (idx >> 9) & 1, d = idx & 511;
  const float* bih = dir ? bih_b : bih_f;
  const float* bhh = dir ? bhh_b : bhh_f;
  const size_t gbase = (size_t)b * NG + (dir << 11);
  float gi = bih[d] + bhh[d];
  float gf = bih[512 + d] + bhh[512 + d];
  float gg = bih[1024 + d] + bhh[1024 + d];
  float go = bih[1536 + d] + bhh[1536 + d];
#pragma unroll
  for (int z = 0; z < 4; ++z) {
    const float* g = gp + (size_t)z * NB * NG + gbase;
    gi += g[d]; gf += g[512 + d]; gg += g[1024 + d]; go += g[1536 + d];
  }
  const float c0v = cq_old[idx];
  const float si = 1.f / (1.f + __expf(-gi));
  const float sf = 1.f / (1.f + __expf(-gf));
  const float so = 1.f / (1.f + __expf(-go));
  const float tg = ftanh(gg);
  const float c2 = sf * c0v + si * tg;
  const float h2 = so * ftanh(c2);
  hq_new[idx] = h2;
  cq_new[idx] = c2;
  hqh_new[idx] = F2B(h2);
}

// ---------------------------------------------------------------------------
extern "C" void kernel_launch(void* const* d_in, const int* in_sizes, int n_in,
                              void* d_out, int out_size, void* d_ws, size_t ws_size,
                              hipStream_t stream)
{
  const float* enc    = (const float*)d_in[0];
  const float* h0     = (const float*)d_in[1];
  const float* c0     = (const float*)d_in[2];
  const int*   target = (const int*)d_in[3];
  const unsigned char* mask = (const unsigned char*)d_in[4];
  const int*   sos    = (const int*)d_in[5];
  const float* emb    = (const float*)d_in[6];
  const float* Wa     = (const float*)d_in[7];
  const float* Ua     = (const float*)d_in[8];
  const float* Va     = (const float*)d_in[9];
  const float* out_W  = (const float*)d_in[10];
  const float* out_b  = (const float*)d_in[11];
  const float* Wih_f  = (const float*)d_in[12];
  const float* Whh_f  = (const float*)d_in[13];
  const float* bih_f  = (const float*)d_in[14];
  const float* bhh_f  = (const float*)d_in[15];
  const float* Wih_b  = (const float*)d_in[16];
  const float* Whh_b  = (const float*)d_in[17];
  const float* bih_b  = (const float*)d_in[18];
  const float* bhh_b  = (const float*)d_in[19];

  float* out_dec  = (float*)d_out;                       // [B][T][V]
  float* out_h    = out_dec + (size_t)NB * NT * NV;      // [2][B][D]
  float* out_c    = out_h + 2 * NB * ND;                 // [2][B][D]
  float* out_attn = out_c + 2 * NB * ND;                 // [B][T][S]

  char* base = (char*)d_ws;
  size_t off = 0;
  auto alloc = [&](size_t bytes) -> char* {
    char* p = base + off;
    off += (bytes + 255) & ~(size_t)255;
    return p;
  };
  short* Uk_h  = (short*)alloc((size_t)NB * NS * NH * 2);   // 33.5 MB
  short* ow_h  = (short*)alloc((size_t)NV * NH * 2);        // 20.5 MB
  short* Ua_h  = (short*)alloc((size_t)NH * NH * 2);
  short* Wa_h  = (short*)alloc((size_t)NH * NH * 2);
  short* Wif_h = (short*)alloc((size_t)2048 * NEH * 2);
  short* Whf_h = (short*)alloc((size_t)2048 * 512 * 2);
  short* Wib_h = (short*)alloc((size_t)2048 * NEH * 2);
  short* Whb_h = (short*)alloc((size_t)2048 * 512 * 2);
  float* q     = (float*)alloc((size_t)NB * NH * 4);
  float* sc    = (float*)alloc((size_t)NB * NS * 4);
  short* x_h   = (short*)alloc((size_t)NB * NEH * 2);
  float* gp    = (float*)alloc((size_t)4 * NB * NG * 4);
  float* hq    = (float*)alloc((size_t)2 * NB * NH * 4);
  float* cq    = (float*)alloc((size_t)2 * NB * NH * 4);
  short* hqh   = (short*)alloc((size_t)2 * NB * NH * 2);
  short* enc_h = nullptr;
  int use_h = 0;
  if (off + (size_t)NB * NS * NH * 2 <= ws_size) {
    enc_h = (short*)alloc((size_t)NB * NS * NH * 2);
    use_h = 1;
  }
  if (off > ws_size) return;  // insufficient scratch

  // one-time bf16 conversions
  f2b_k<<<dim3(2048), dim3(256), 0, stream>>>(out_W, ow_h, NV * NH / 4);
  f2b_k<<<dim3(1024), dim3(256), 0, stream>>>(Ua, Ua_h, NH * NH / 4);
  f2b_k<<<dim3(1024), dim3(256), 0, stream>>>(Wa, Wa_h, NH * NH / 4);
  f2b_k<<<dim3(1024), dim3(256), 0, stream>>>(Wih_f, Wif_h, 2048 * NEH / 4);
  f2b_k<<<dim3(1024), dim3(256), 0, stream>>>(Whh_f, Whf_h, 2048 * 512 / 4);
  f2b_k<<<dim3(1024), dim3(256), 0, stream>>>(Wih_b, Wib_h, 2048 * NEH / 4);
  f2b_k<<<dim3(1024), dim3(256), 0, stream>>>(Whh_b, Whb_h, 2048 * 512 / 4);
  if (use_h)
    f2b_k<<<dim3(2048), dim3(256), 0, stream>>>(enc, enc_h, NB * NS * NH / 4);

  init_state<<<dim3(256), dim3(256), 0, stream>>>(h0, c0, hq, cq, hqh);

  // Uk[bs,k] = sum_h enc[bs,h]*Ua[k,h]  (fp32 A converted in staging)
  uk_mm<<<dim3(16, 256), dim3(256), 0, stream>>>(enc, Ua_h, Uk_h);

  for (int t = 0; t < NT; ++t) {
    float* hq_cur = hq + (t & 1) * (NB * NH);
    float* hq_nxt = hq + ((t & 1) ^ 1) * (NB * NH);
    float* cq_cur = cq + (t & 1) * (NB * NH);
    float* cq_nxt = cq + ((t & 1) ^ 1) * (NB * NH);
    short* hqh_cur = hqh + (t & 1) * (NB * NH);
    short* hqh_nxt = hqh + ((t & 1) ^ 1) * (NB * NH);

    q_mm<<<dim3(16), dim3(256), 0, stream>>>(hqh_cur, Wa_h, q);
    attn_score<<<dim3(NB * NS / 4), dim3(256), 0, stream>>>(q, Uk_h, Va, mask, sc);
    ctx_soft<<<dim3(384), dim3(256), 0, stream>>>(sc, enc, enc_h, use_h, emb,
                                                  target, sos, x_h, out_attn, t);
    gates_mm<<<dim3(64, 1, 4), dim3(256), 0, stream>>>(x_h, hqh_cur, Wif_h, Whf_h,
                                                       Wib_h, Whb_h, gp);
    gate_elt<<<dim3(256), dim3(256), 0, stream>>>(gp, bih_f, bhh_f, bih_b, bhh_b,
                                                  cq_cur, hq_nxt, cq_nxt, hqh_nxt);
    logits_mm<<<dim3(157), dim3(256), 0, stream>>>(hqh_nxt, ow_h, out_b, out_dec, t);
  }

  final_state<<<dim3(256), dim3(256), 0, stream>>>(hq, cq, out_h, out_c);
}

// Round 3
// 2698.928 us; speedup vs baseline: 2.9939x; 1.5103x over previous
//
#include <hip/hip_runtime.h>

#define NB 64
#define NS 256
#define NH 1024
#define NE 512
#define NV 10000
#define NT 64
#define ND 512
#define NEH 1536

typedef __attribute__((ext_vector_type(8))) short bf16x8;
typedef __attribute__((ext_vector_type(4))) float f32x4;

__device__ __forceinline__ short F2B(float f) {
  unsigned u = __float_as_uint(f);
  return (short)((u + 0x7fffu + ((u >> 16) & 1u)) >> 16);
}
__device__ __forceinline__ float B2F(short s) {
  return __uint_as_float(((unsigned)(unsigned short)s) << 16);
}
__device__ __forceinline__ float ftanh(float x) {
  float e = __expf(2.f * x);                 // inf for big x -> rcp -> 0 -> 1
  return 1.f - 2.f * __builtin_amdgcn_rcpf(e + 1.f);
}

#define GLD16(src, dst)                                                        \
  __builtin_amdgcn_global_load_lds(                                            \
      (const __attribute__((address_space(1))) void*)(src),                    \
      (__attribute__((address_space(3))) void*)(dst), 16, 0, 0)

// ---------------------------------------------------------------------------
// 64x64 bf16 MFMA tile, BK=64, double-buffered LDS (one barrier per k-iter).
// XOR swizzle: logical (row, chunk c) at phys chunk (row<<3)|(c^(row&7)).
// ---------------------------------------------------------------------------
template <bool AF32>
__device__ __forceinline__ void mm64_core(
    const void* Av, int lda, const short* __restrict__ Wg, int ldw, int K,
    int nlim, float* Cf, short* Ch, size_t ldc, const float* bias, char* smem)
{
  const int tid = threadIdx.x;
  const int lane = tid & 63, w = tid >> 6;
  const int qm = (w >> 1) << 5, qn = (w & 1) << 5;
  const int kg = lane >> 4, rl = lane & 15;
  f32x4 acc[2][2] = {};
  const int nIt = K >> 6;

  auto stage = [&](int k0, int buf) {
    char* As = smem + (buf << 14);
    char* Bs = As + 8192;
    if (AF32) {
      const float* Af = (const float*)Av;
#pragma unroll
      for (int p = 0; p < 2; ++p) {
        int j = tid + (p << 8);
        int row = j >> 3;
        int c = (j & 7) ^ (row & 7);
        const float* src = Af + (size_t)row * lda + k0 + (c << 3);
        float4 v0 = ((const float4*)src)[0];
        float4 v1 = ((const float4*)src)[1];
        bf16x8 pk;
        pk[0] = F2B(v0.x); pk[1] = F2B(v0.y); pk[2] = F2B(v0.z); pk[3] = F2B(v0.w);
        pk[4] = F2B(v1.x); pk[5] = F2B(v1.y); pk[6] = F2B(v1.z); pk[7] = F2B(v1.w);
        *((bf16x8*)As + j) = pk;
      }
    } else {
      const short* Ab = (const short*)Av;
#pragma unroll
      for (int p = 0; p < 2; ++p) {
        int j = (w << 7) + (p << 6) + lane;
        int row = j >> 3;
        int c = (j & 7) ^ (row & 7);
        GLD16(Ab + (size_t)row * lda + k0 + (c << 3), As + (w << 11) + (p << 10));
      }
    }
#pragma unroll
    for (int p = 0; p < 2; ++p) {
      int j = (w << 7) + (p << 6) + lane;
      int row = j >> 3;
      int wr = min(row, nlim - 1);
      int c = (j & 7) ^ (row & 7);
      GLD16(Wg + (size_t)wr * ldw + k0 + (c << 3), Bs + (w << 11) + (p << 10));
    }
  };

  stage(0, 0);
  for (int it = 0; it < nIt; ++it) {
    __syncthreads();
    if (it + 1 < nIt) stage((it + 1) << 6, (it + 1) & 1);
    const short* As = (const short*)(smem + ((it & 1) << 14));
    const short* Bs = As + 4096;
#pragma unroll
    for (int kk = 0; kk < 2; ++kk) {
      bf16x8 af[2], bfr[2];
#pragma unroll
      for (int mt = 0; mt < 2; ++mt) {
        int r2 = qm + (mt << 4) + rl;
        int c = (kk << 2) + kg;
        af[mt] = *((const bf16x8*)As + ((r2 << 3) | (c ^ (r2 & 7))));
      }
#pragma unroll
      for (int nt = 0; nt < 2; ++nt) {
        int r2 = qn + (nt << 4) + rl;
        int c = (kk << 2) + kg;
        bfr[nt] = *((const bf16x8*)Bs + ((r2 << 3) | (c ^ (r2 & 7))));
      }
#pragma unroll
      for (int mt = 0; mt < 2; ++mt)
#pragma unroll
        for (int nt = 0; nt < 2; ++nt)
          acc[mt][nt] = __builtin_amdgcn_mfma_f32_16x16x32_bf16(
              af[mt], bfr[nt], acc[mt][nt], 0, 0, 0);
    }
  }
#pragma unroll
  for (int mt = 0; mt < 2; ++mt) {
#pragma unroll
    for (int nt = 0; nt < 2; ++nt) {
      int cn = qn + (nt << 4) + rl;
      if (cn < nlim) {
        float bv = bias ? bias[cn] : 0.f;
#pragma unroll
        for (int r = 0; r < 4; ++r) {
          int rowm = qm + (mt << 4) + (kg << 2) + r;
          float v = acc[mt][nt][r] + bv;
          if (Cf) Cf[(size_t)rowm * ldc + cn] = v;
          else Ch[(size_t)rowm * ldc + cn] = F2B(v);
        }
      }
    }
  }
}

__global__ __launch_bounds__(256) void uk_mm(const float* __restrict__ enc,
                                             const short* __restrict__ Ua_h,
                                             short* __restrict__ Uk_h) {
  __shared__ char smem[32768];
  mm64_core<true>(enc + (size_t)blockIdx.y * 64 * NH, NH,
                  Ua_h + (size_t)blockIdx.x * 64 * NH, NH, NH, 64, nullptr,
                  Uk_h + (size_t)blockIdx.y * 64 * NH + blockIdx.x * 64, NH,
                  nullptr, smem);
}

__global__ __launch_bounds__(256) void q_mm(const short* __restrict__ hcur,
                                            const short* __restrict__ Wa_h,
                                            float* __restrict__ q) {
  __shared__ char smem[32768];
  mm64_core<false>(hcur, NH, Wa_h + (size_t)blockIdx.x * 64 * NH, NH, NH, 64,
                   q + blockIdx.x * 64, nullptr, NH, nullptr, smem);
}

// ---------------------------------------------------------------------------
// Big logits GEMM: L[m, v] = Hall[m,:] . ow[v,:] + b[v]; m = t*64+b.
// 128x128 tile, 4 waves each 64x64, BK=64, single-buffered (occupancy overlap).
// ---------------------------------------------------------------------------
__global__ __launch_bounds__(256) void logits_big(
    const short* __restrict__ A, const short* __restrict__ Bw,
    const float* __restrict__ bias, float* __restrict__ dec)
{
  __shared__ char smem[32768];
  const int tid = threadIdx.x, lane = tid & 63, w = tid >> 6;
  const int m0 = blockIdx.y << 7;
  const int n0 = blockIdx.x << 7;
  const int qm = (w >> 1) << 6, qn = (w & 1) << 6;
  const int kg = lane >> 4, rl = lane & 15;
  f32x4 acc[4][4] = {};
  for (int k0 = 0; k0 < NH; k0 += 64) {
#pragma unroll
    for (int p = 0; p < 4; ++p) {
      int j = (((w << 2) + p) << 6) + lane;
      int row = j >> 3;
      int c = (j & 7) ^ (row & 7);
      GLD16(A + (size_t)(m0 + row) * NH + k0 + (c << 3),
            smem + (((w << 2) + p) << 10));
      int vr = n0 + row; if (vr > NV - 1) vr = NV - 1;
      GLD16(Bw + (size_t)vr * NH + k0 + (c << 3),
            smem + 16384 + (((w << 2) + p) << 10));
    }
    __syncthreads();
    const short* As = (const short*)smem;
    const short* Bs = (const short*)(smem + 16384);
#pragma unroll
    for (int kk = 0; kk < 2; ++kk) {
      bf16x8 af[4], bfr[4];
#pragma unroll
      for (int mt = 0; mt < 4; ++mt) {
        int r2 = qm + (mt << 4) + rl;
        int c = (kk << 2) + kg;
        af[mt] = *((const bf16x8*)As + ((r2 << 3) | (c ^ (r2 & 7))));
      }
#pragma unroll
      for (int nt = 0; nt < 4; ++nt) {
        int r2 = qn + (nt << 4) + rl;
        int c = (kk << 2) + kg;
        bfr[nt] = *((const bf16x8*)Bs + ((r2 << 3) | (c ^ (r2 & 7))));
      }
#pragma unroll
      for (int mt = 0; mt < 4; ++mt)
#pragma unroll
        for (int nt = 0; nt < 4; ++nt)
          acc[mt][nt] = __builtin_amdgcn_mfma_f32_16x16x32_bf16(
              af[mt], bfr[nt], acc[mt][nt], 0, 0, 0);
    }
    __syncthreads();
  }
#pragma unroll
  for (int nt = 0; nt < 4; ++nt) {
    int colv = n0 + qn + (nt << 4) + rl;
    if (colv < NV) {
      float bv = bias[colv];
#pragma unroll
      for (int mt = 0; mt < 4; ++mt)
#pragma unroll
        for (int r = 0; r < 4; ++r) {
          int m = m0 + qm + (mt << 4) + (kg << 2) + r;
          int b = m & 63, t = m >> 6;
          dec[(size_t)((b << 6) + t) * NV + colv] = acc[mt][nt][r] + bv;
        }
    }
  }
}

// ---------------------------------------------------------------------------
// Fused gates GEMM + LSTM cell. 64 blocks (dir, dblk), 512 thr (8 waves).
// Weights pre-permuted: n' = dblk*64 + dlo*4 + gate, K = 1536(x) + 512(h).
// Waves 0-3: K half [0,1024); waves 4-7: [1024,2048). LDS reduce + cell.
// ---------------------------------------------------------------------------
__global__ __launch_bounds__(512) void gates_fused(
    const short* __restrict__ x_h, const short* __restrict__ hcur,
    const short* __restrict__ Wcomb, const float* __restrict__ bias_perm,
    const float* __restrict__ cq_old, float* __restrict__ hq_f,
    float* __restrict__ cq_new, short* __restrict__ hnext)
{
  __shared__ char smem[65536];
  const int tid = threadIdx.x;
  const int lane = tid & 63, w = tid >> 6;
  const int khalf = w >> 2, q2 = w & 3;
  const int qm = (q2 >> 1) << 5, qn = (q2 & 1) << 5;
  const int kg = lane >> 4, rl = lane & 15;
  const int dir = blockIdx.x >> 5, dblk = blockIdx.x & 31;
  const int hoff = dir << 9;
  const short* Wrow = Wcomb + ((size_t)((dir << 11) + (dblk << 6)) << 11);
  f32x4 acc[2][2] = {};

  const int jj = (w << 6) + lane;
  const int row = jj >> 3;
  const int c8 = (jj & 7) ^ (row & 7);

  auto stage = [&](int k0, int buf) {
    char* base = smem + (buf << 15);
    {
      int k = k0 + (c8 << 3);                    // < 1024, always x region
      GLD16(x_h + (size_t)row * NEH + k, base + (w << 10));
    }
    {
      int k = 1024 + k0 + (c8 << 3);
      const short* src = (k < NEH) ? (x_h + (size_t)row * NEH + k)
                                   : (hcur + (size_t)row * NH + hoff + (k - NEH));
      GLD16(src, base + 8192 + (w << 10));
    }
    {
      int k = k0 + (c8 << 3);
      GLD16(Wrow + (size_t)row * 2048 + k, base + 16384 + (w << 10));
    }
    {
      int k = 1024 + k0 + (c8 << 3);
      GLD16(Wrow + (size_t)row * 2048 + k, base + 24576 + (w << 10));
    }
  };

  stage(0, 0);
  for (int it = 0; it < 16; ++it) {
    __syncthreads();
    if (it + 1 < 16) stage((it + 1) << 6, (it + 1) & 1);
    const char* base = smem + ((it & 1) << 15);
    const short* As = (const short*)(base + (khalf << 13));
    const short* Bs = (const short*)(base + 16384 + (khalf << 13));
#pragma unroll
    for (int kk = 0; kk < 2; ++kk) {
      bf16x8 af[2], bfr[2];
#pragma unroll
      for (int mt = 0; mt < 2; ++mt) {
        int r2 = qm + (mt << 4) + rl;
        int c = (kk << 2) + kg;
        af[mt] = *((const bf16x8*)As + ((r2 << 3) | (c ^ (r2 & 7))));
      }
#pragma unroll
      for (int nt = 0; nt < 2; ++nt) {
        int r2 = qn + (nt << 4) + rl;
        int c = (kk << 2) + kg;
        bfr[nt] = *((const bf16x8*)Bs + ((r2 << 3) | (c ^ (r2 & 7))));
      }
#pragma unroll
      for (int mt = 0; mt < 2; ++mt)
#pragma unroll
        for (int nt = 0; nt < 2; ++nt)
          acc[mt][nt] = __builtin_amdgcn_mfma_f32_16x16x32_bf16(
              af[mt], bfr[nt], acc[mt][nt], 0, 0, 0);
    }
  }
  __syncthreads();
  float* gacc = (float*)smem;                    // [64][68], overlays buf0
  if (khalf == 1) {
#pragma unroll
    for (int mt = 0; mt < 2; ++mt)
#pragma unroll
      for (int nt = 0; nt < 2; ++nt)
#pragma unroll
        for (int r = 0; r < 4; ++r)
          gacc[(qm + (mt << 4) + (kg << 2) + r) * 68 + qn + (nt << 4) + rl] =
              acc[mt][nt][r];
  }
  __syncthreads();
  if (khalf == 0) {
#pragma unroll
    for (int mt = 0; mt < 2; ++mt)
#pragma unroll
      for (int nt = 0; nt < 2; ++nt)
#pragma unroll
        for (int r = 0; r < 4; ++r)
          gacc[(qm + (mt << 4) + (kg << 2) + r) * 68 + qn + (nt << 4) + rl] +=
              acc[mt][nt][r];
  }
  __syncthreads();
  const float* bp = bias_perm + (dir << 11) + (dblk << 6);
#pragma unroll
  for (int e = tid; e < 1024; e += 512) {
    int b = e >> 4, dlo = e & 15;
    int cb = dlo << 2;
    float gi = gacc[b * 68 + cb + 0] + bp[cb + 0];
    float gf = gacc[b * 68 + cb + 1] + bp[cb + 1];
    float gg = gacc[b * 68 + cb + 2] + bp[cb + 2];
    float go = gacc[b * 68 + cb + 3] + bp[cb + 3];
    int idx = (b << 10) + hoff + (dblk << 4) + dlo;
    float c0v = cq_old[idx];
    float si = 1.f / (1.f + __expf(-gi));
    float sf = 1.f / (1.f + __expf(-gf));
    float so = 1.f / (1.f + __expf(-go));
    float tg = ftanh(gg);
    float c2 = sf * c0v + si * tg;
    float h2 = so * ftanh(c2);
    hq_f[idx] = h2;
    cq_new[idx] = c2;
    hnext[idx] = F2B(h2);
  }
}

// --- small kernels ----------------------------------------------------------
__global__ __launch_bounds__(256) void f2b_k(const float* __restrict__ in,
                                             short* __restrict__ out, int n4) {
  int i = blockIdx.x * 256 + threadIdx.x;
  const int stride = gridDim.x * 256;
  for (; i < n4; i += stride) {
    float4 v = ((const float4*)in)[i];
    short4 o;
    o.x = F2B(v.x); o.y = F2B(v.y); o.z = F2B(v.z); o.w = F2B(v.w);
    ((short4*)out)[i] = o;
  }
}

__global__ __launch_bounds__(256) void perm_w(
    const float* __restrict__ Wih_f, const float* __restrict__ Whh_f,
    const float* __restrict__ Wih_b, const float* __restrict__ Whh_b,
    const float* __restrict__ bih_f, const float* __restrict__ bhh_f,
    const float* __restrict__ bih_b, const float* __restrict__ bhh_b,
    short* __restrict__ Wcomb, float* __restrict__ bias_perm)
{
  int i = blockIdx.x * 256 + threadIdx.x;        // [0, 2*2048*512)
  int k4 = i & 511;
  int np = (i >> 9) & 2047;
  int dir = i >> 20;
  int gate = np & 3, dlo = (np >> 2) & 15, dblk = np >> 6;
  int d = (dblk << 4) + dlo;
  int r = (gate << 9) + d;
  int k = k4 << 2;
  const float* Wih = dir ? Wih_b : Wih_f;
  const float* Whh = dir ? Whh_b : Whh_f;
  float4 v = (k < NEH) ? *(const float4*)(Wih + (size_t)r * NEH + k)
                       : *(const float4*)(Whh + (size_t)r * ND + (k - NEH));
  short4 o;
  o.x = F2B(v.x); o.y = F2B(v.y); o.z = F2B(v.z); o.w = F2B(v.w);
  *(short4*)(Wcomb + ((size_t)((dir << 11) + np) << 11) + k) = o;
  if (k4 == 0) {
    const float* bi = dir ? bih_b : bih_f;
    const float* bh = dir ? bhh_b : bhh_f;
    bias_perm[(dir << 11) + np] = bi[r] + bh[r];
  }
}

__global__ __launch_bounds__(256) void init_state(
    const float* __restrict__ h0, const float* __restrict__ c0,
    float* __restrict__ hq, float* __restrict__ cq, short* __restrict__ H0) {
  int idx = blockIdx.x * 256 + threadIdx.x;      // b*H + dir*D + d
  int b = idx >> 10, dir = (idx >> 9) & 1, d = idx & 511;
  int src = dir * NB * ND + (b << 9) + d;
  float h = h0[src];
  hq[idx] = h;
  cq[idx] = c0[src];
  H0[idx] = F2B(h);
}

__global__ __launch_bounds__(256) void final_state(
    const float* __restrict__ hq, const float* __restrict__ cq,
    float* __restrict__ out_h, float* __restrict__ out_c) {
  int idx = blockIdx.x * 256 + threadIdx.x;      // dir*B*D + b*D + d
  int dir = idx >> 15, r = idx & 32767, b = r >> 9, d = r & 511;
  int src = b * NH + dir * ND + d;
  out_h[idx] = hq[src];
  out_c[idx] = cq[src];
}

// one wave per (b,s)
__global__ __launch_bounds__(256) void attn_score(
    const float* __restrict__ q, const short* __restrict__ Uk,
    const float* __restrict__ Va, const unsigned char* __restrict__ mask,
    float* __restrict__ sc) {
  const int lane = threadIdx.x & 63, wid = threadIdx.x >> 6;
  const int bs = blockIdx.x * 4 + wid;
  const int b = bs >> 8;
  const short* ukp = Uk + (size_t)bs * NH;
  const float* qp = q + (size_t)b * NH;
  float acc = 0.f;
#pragma unroll
  for (int i = 0; i < 4; ++i) {
    int h = i * 256 + (lane << 2);
    short4 uv = *(const short4*)(ukp + h);
    float4 qv = *(const float4*)(qp + h);
    float4 vv = *(const float4*)(Va + h);
    acc += vv.x * ftanh(qv.x + B2F(uv.x));
    acc += vv.y * ftanh(qv.y + B2F(uv.y));
    acc += vv.z * ftanh(qv.z + B2F(uv.z));
    acc += vv.w * ftanh(qv.w + B2F(uv.w));
  }
#pragma unroll
  for (int o = 32; o; o >>= 1) acc += __shfl_down(acc, o);
  if (lane == 0) sc[bs] = mask[bs] ? -__builtin_inff() : acc;
}

// blocks 0..255: (b, h-quarter) softmax + ctx; blocks 256..383: emb gather
__global__ __launch_bounds__(256) void ctx_soft(
    const float* __restrict__ sc, const float* __restrict__ enc_f,
    const short* __restrict__ enc_h, int use_h, const float* __restrict__ emb,
    const int* __restrict__ target, const int* __restrict__ sos,
    short* __restrict__ x_h, float* __restrict__ attn_out, int t) {
  const int blk = blockIdx.x, tid = threadIdx.x;
  if (blk < 256) {
    const int b = blk >> 2, qh = blk & 3;
    __shared__ float red[4];
    __shared__ float ws[NS];
    __shared__ float4 red4[4][64];
    float v = sc[b * NS + tid];
    float m = v;
#pragma unroll
    for (int o = 32; o; o >>= 1) m = fmaxf(m, __shfl_down(m, o));
    if ((tid & 63) == 0) red[tid >> 6] = m;
    __syncthreads();
    m = fmaxf(fmaxf(red[0], red[1]), fmaxf(red[2], red[3]));
    float e = __expf(v - m);
    float su = e;
#pragma unroll
    for (int o = 32; o; o >>= 1) su += __shfl_down(su, o);
    __syncthreads();
    if ((tid & 63) == 0) red[tid >> 6] = su;
    __syncthreads();
    su = red[0] + red[1] + red[2] + red[3];
    float wgt = e / su;
    ws[tid] = wgt;
    if (qh == 0) attn_out[((size_t)b * NT + t) * NS + tid] = wgt;
    __syncthreads();
    const int w = tid >> 6, l = tid & 63;
    const int h = (qh << 8) + (l << 2);
    const int s0 = w << 6;
    float4 a = make_float4(0.f, 0.f, 0.f, 0.f);
    if (use_h) {
      const short* ep = enc_h + ((size_t)b * NS + s0) * NH + h;
      for (int s = 0; s < 64; ++s) {
        short4 vv = *(const short4*)(ep + (size_t)s * NH);
        float wv = ws[s0 + s];
        a.x += wv * B2F(vv.x); a.y += wv * B2F(vv.y);
        a.z += wv * B2F(vv.z); a.w += wv * B2F(vv.w);
      }
    } else {
      const float* ep = enc_f + ((size_t)b * NS + s0) * NH + h;
      for (int s = 0; s < 64; ++s) {
        float4 vv = *(const float4*)(ep + (size_t)s * NH);
        float wv = ws[s0 + s];
        a.x += wv * vv.x; a.y += wv * vv.y; a.z += wv * vv.z; a.w += wv * vv.w;
      }
    }
    red4[w][l] = a;
    __syncthreads();
    if (tid < 64) {
      float4 r0 = red4[0][tid], r1 = red4[1][tid], r2 = red4[2][tid],
             r3 = red4[3][tid];
      float sx = r0.x + r1.x + r2.x + r3.x;
      float sy = r0.y + r1.y + r2.y + r3.y;
      float sz = r0.z + r1.z + r2.z + r3.z;
      float sw = r0.w + r1.w + r2.w + r3.w;
      int hh = (qh << 8) + (tid << 2);
      short4 o;
      o.x = F2B(sx); o.y = F2B(sy); o.z = F2B(sz); o.w = F2B(sw);
      *(short4*)(x_h + (size_t)b * NEH + NE + hh) = o;
    }
  } else {
    const int idx = (blk - 256) * 256 + tid;
    const int b = idx >> 9, e = idx & 511;
    const int tok = (t == 0) ? sos[0] : target[b * NT + t - 1];
    x_h[(size_t)b * NEH + e] = F2B(emb[(size_t)tok * NE + e]);
  }
}

// ---------------------------------------------------------------------------
extern "C" void kernel_launch(void* const* d_in, const int* in_sizes, int n_in,
                              void* d_out, int out_size, void* d_ws, size_t ws_size,
                              hipStream_t stream)
{
  const float* enc    = (const float*)d_in[0];
  const float* h0     = (const float*)d_in[1];
  const float* c0     = (const float*)d_in[2];
  const int*   target = (const int*)d_in[3];
  const unsigned char* mask = (const unsigned char*)d_in[4];
  const int*   sos    = (const int*)d_in[5];
  const float* emb    = (const float*)d_in[6];
  const float* Wa     = (const float*)d_in[7];
  const float* Ua     = (const float*)d_in[8];
  const float* Va     = (const float*)d_in[9];
  const float* out_W  = (const float*)d_in[10];
  const float* out_b  = (const float*)d_in[11];
  const float* Wih_f  = (const float*)d_in[12];
  const float* Whh_f  = (const float*)d_in[13];
  const float* bih_f  = (const float*)d_in[14];
  const float* bhh_f  = (const float*)d_in[15];
  const float* Wih_b  = (const float*)d_in[16];
  const float* Whh_b  = (const float*)d_in[17];
  const float* bih_b  = (const float*)d_in[18];
  const float* bhh_b  = (const float*)d_in[19];

  float* out_dec  = (float*)d_out;                       // [B][T][V]
  float* out_h    = out_dec + (size_t)NB * NT * NV;      // [2][B][D]
  float* out_c    = out_h + 2 * NB * ND;                 // [2][B][D]
  float* out_attn = out_c + 2 * NB * ND;                 // [B][T][S]

  char* base = (char*)d_ws;
  size_t off = 0;
  auto alloc = [&](size_t bytes) -> char* {
    char* p = base + off;
    off += (bytes + 255) & ~(size_t)255;
    return p;
  };
  short* Uk_h   = (short*)alloc((size_t)NB * NS * NH * 2);   // 33.5 MB
  short* ow_h   = (short*)alloc((size_t)NV * NH * 2);        // 20.5 MB
  short* Ua_h   = (short*)alloc((size_t)NH * NH * 2);
  short* Wa_h   = (short*)alloc((size_t)NH * NH * 2);
  short* Wcomb  = (short*)alloc((size_t)2 * 2048 * 2048 * 2); // 16.8 MB
  float* bperm  = (float*)alloc((size_t)2 * 2048 * 4);
  float* q      = (float*)alloc((size_t)NB * NH * 4);
  float* sc     = (float*)alloc((size_t)NB * NS * 4);
  short* x_h    = (short*)alloc((size_t)NB * NEH * 2);
  float* hq     = (float*)alloc((size_t)NB * NH * 4);
  float* cq     = (float*)alloc((size_t)2 * NB * NH * 4);
  short* Hbuf   = (short*)alloc((size_t)(NT + 1) * NB * NH * 2); // 8.5 MB
  short* enc_h  = nullptr;
  int use_h = 0;
  if (off + (size_t)NB * NS * NH * 2 <= ws_size) {
    enc_h = (short*)alloc((size_t)NB * NS * NH * 2);
    use_h = 1;
  }
  if (off > ws_size) return;  // insufficient scratch

  // setup: conversions + weight permute + initial state + Uk
  f2b_k<<<dim3(2048), dim3(256), 0, stream>>>(out_W, ow_h, NV * NH / 4);
  f2b_k<<<dim3(1024), dim3(256), 0, stream>>>(Ua, Ua_h, NH * NH / 4);
  f2b_k<<<dim3(1024), dim3(256), 0, stream>>>(Wa, Wa_h, NH * NH / 4);
  perm_w<<<dim3(8192), dim3(256), 0, stream>>>(Wih_f, Whh_f, Wih_b, Whh_b,
                                               bih_f, bhh_f, bih_b, bhh_b,
                                               Wcomb, bperm);
  if (use_h)
    f2b_k<<<dim3(2048), dim3(256), 0, stream>>>(enc, enc_h, NB * NS * NH / 4);
  init_state<<<dim3(256), dim3(256), 0, stream>>>(h0, c0, hq, cq, Hbuf);
  uk_mm<<<dim3(16, 256), dim3(256), 0, stream>>>(enc, Ua_h, Uk_h);

  for (int t = 0; t < NT; ++t) {
    const short* hcur = Hbuf + (size_t)t * NB * NH;
    short* hnext = Hbuf + (size_t)(t + 1) * NB * NH;
    float* cq_cur = cq + (t & 1) * (NB * NH);
    float* cq_nxt = cq + ((t & 1) ^ 1) * (NB * NH);

    q_mm<<<dim3(16), dim3(256), 0, stream>>>(hcur, Wa_h, q);
    attn_score<<<dim3(NB * NS / 4), dim3(256), 0, stream>>>(q, Uk_h, Va, mask, sc);
    ctx_soft<<<dim3(384), dim3(256), 0, stream>>>(sc, enc, enc_h, use_h, emb,
                                                  target, sos, x_h, out_attn, t);
    gates_fused<<<dim3(64), dim3(512), 0, stream>>>(x_h, hcur, Wcomb, bperm,
                                                    cq_cur, hq, cq_nxt, hnext);
  }

  // all 64 steps of logits in one GEMM: A = Hbuf rows 64..4159 (= h after step t)
  logits_big<<<dim3(79, 32), dim3(256), 0, stream>>>(Hbuf + NB * NH, ow_h,
                                                     out_b, out_dec);
  final_state<<<dim3(256), dim3(256), 0, stream>>>(hq, cq, out_h, out_c);
}

// Round 5
// 2095.298 us; speedup vs baseline: 3.8565x; 1.2881x over previous
//
#include <hip/hip_runtime.h>

#define NB 64
#define NS 256
#define NH 1024
#define NE 512
#define NV 10000
#define NT 64
#define ND 512
#define NEH 1536

typedef __attribute__((ext_vector_type(8))) short bf16x8;
typedef __attribute__((ext_vector_type(4))) float f32x4;

__device__ __forceinline__ short F2B(float f) {
  unsigned u = __float_as_uint(f);
  return (short)((u + 0x7fffu + ((u >> 16) & 1u)) >> 16);
}
__device__ __forceinline__ float B2F(short s) {
  return __uint_as_float(((unsigned)(unsigned short)s) << 16);
}
__device__ __forceinline__ float ftanh(float x) {
  float e = __expf(2.f * x);                 // inf for big x -> rcp -> 0 -> 1
  return 1.f - 2.f * __builtin_amdgcn_rcpf(e + 1.f);
}

#define GLD16(src, dst)                                                        \
  __builtin_amdgcn_global_load_lds(                                            \
      (const __attribute__((address_space(1))) void*)(src),                    \
      (__attribute__((address_space(3))) void*)(dst), 16, 0, 0)

// ---------------------------------------------------------------------------
// Fallback 64x64 tile (fp32 A staging) — used only for Uk when enc_h absent.
// ---------------------------------------------------------------------------
__device__ __forceinline__ void mm64_f32a(
    const float* __restrict__ Af, int lda, const short* __restrict__ Wg,
    int ldw, int K, short* Ch, size_t ldc, char* smem)
{
  const int tid = threadIdx.x;
  const int lane = tid & 63, w = tid >> 6;
  const int qm = (w >> 1) << 5, qn = (w & 1) << 5;
  const int kg = lane >> 4, rl = lane & 15;
  f32x4 acc[2][2] = {};
  const int nIt = K >> 6;

  auto stage = [&](int k0, int buf) {
    char* As = smem + (buf << 14);
    char* Bs = As + 8192;
#pragma unroll
    for (int p = 0; p < 2; ++p) {
      int j = tid + (p << 8);
      int row = j >> 3;
      int c = (j & 7) ^ (row & 7);
      const float* src = Af + (size_t)row * lda + k0 + (c << 3);
      float4 v0 = ((const float4*)src)[0];
      float4 v1 = ((const float4*)src)[1];
      bf16x8 pk;
      pk[0] = F2B(v0.x); pk[1] = F2B(v0.y); pk[2] = F2B(v0.z); pk[3] = F2B(v0.w);
      pk[4] = F2B(v1.x); pk[5] = F2B(v1.y); pk[6] = F2B(v1.z); pk[7] = F2B(v1.w);
      *((bf16x8*)As + j) = pk;
    }
#pragma unroll
    for (int p = 0; p < 2; ++p) {
      int j = (w << 7) + (p << 6) + lane;
      int row = j >> 3;
      int c = (j & 7) ^ (row & 7);
      GLD16(Wg + (size_t)row * ldw + k0 + (c << 3), Bs + (w << 11) + (p << 10));
    }
  };

  stage(0, 0);
  for (int it = 0; it < nIt; ++it) {
    __syncthreads();
    if (it + 1 < nIt) stage((it + 1) << 6, (it + 1) & 1);
    const short* As = (const short*)(smem + ((it & 1) << 14));
    const short* Bs = As + 4096;
#pragma unroll
    for (int kk = 0; kk < 2; ++kk) {
      bf16x8 af[2], bfr[2];
#pragma unroll
      for (int mt = 0; mt < 2; ++mt) {
        int r2 = qm + (mt << 4) + rl;
        int c = (kk << 2) + kg;
        af[mt] = *((const bf16x8*)As + ((r2 << 3) | (c ^ (r2 & 7))));
      }
#pragma unroll
      for (int nt = 0; nt < 2; ++nt) {
        int r2 = qn + (nt << 4) + rl;
        int c = (kk << 2) + kg;
        bfr[nt] = *((const bf16x8*)Bs + ((r2 << 3) | (c ^ (r2 & 7))));
      }
#pragma unroll
      for (int mt = 0; mt < 2; ++mt)
#pragma unroll
        for (int nt = 0; nt < 2; ++nt)
          acc[mt][nt] = __builtin_amdgcn_mfma_f32_16x16x32_bf16(
              af[mt], bfr[nt], acc[mt][nt], 0, 0, 0);
    }
  }
#pragma unroll
  for (int mt = 0; mt < 2; ++mt)
#pragma unroll
    for (int nt = 0; nt < 2; ++nt) {
      int cn = qn + (nt << 4) + rl;
#pragma unroll
      for (int r = 0; r < 4; ++r) {
        int rowm = qm + (mt << 4) + (kg << 2) + r;
        Ch[(size_t)rowm * ldc + cn] = F2B(acc[mt][nt][r]);
      }
    }
}

__global__ __launch_bounds__(256) void uk_mm_f32(const float* __restrict__ enc,
                                                 const short* __restrict__ Ua_h,
                                                 short* __restrict__ Uk_h) {
  __shared__ char smem[32768];
  mm64_f32a(enc + (size_t)blockIdx.y * 64 * NH, NH,
            Ua_h + (size_t)blockIdx.x * 64 * NH, NH, NH,
            Uk_h + (size_t)blockIdx.y * 64 * NH + blockIdx.x * 64, NH, smem);
}

// ---------------------------------------------------------------------------
// 128x128 bf16 tile GEMM (BK=64, single-buffered): MODE 0 = logits (fp32 +
// bias, (t,b)->(b,t) store), MODE 1 = Uk (bf16 store).
// ---------------------------------------------------------------------------
template <int MODE>
__global__ __launch_bounds__(256) void mm128(
    const short* __restrict__ A, const short* __restrict__ Bw, int nvmax,
    const float* __restrict__ bias, float* __restrict__ Cf,
    short* __restrict__ Ch)
{
  __shared__ char smem[32768];
  const int tid = threadIdx.x, lane = tid & 63, w = tid >> 6;
  const int m0 = blockIdx.y << 7;
  const int n0 = blockIdx.x << 7;
  const int qm = (w >> 1) << 6, qn = (w & 1) << 6;
  const int kg = lane >> 4, rl = lane & 15;
  f32x4 acc[4][4] = {};
  for (int k0 = 0; k0 < NH; k0 += 64) {
#pragma unroll
    for (int p = 0; p < 4; ++p) {
      int j = (((w << 2) + p) << 6) + lane;
      int row = j >> 3;
      int c = (j & 7) ^ (row & 7);
      GLD16(A + (size_t)(m0 + row) * NH + k0 + (c << 3),
            smem + (((w << 2) + p) << 10));
      int vr = n0 + row; if (vr > nvmax - 1) vr = nvmax - 1;
      GLD16(Bw + (size_t)vr * NH + k0 + (c << 3),
            smem + 16384 + (((w << 2) + p) << 10));
    }
    __syncthreads();
    const short* As = (const short*)smem;
    const short* Bs = (const short*)(smem + 16384);
#pragma unroll
    for (int kk = 0; kk < 2; ++kk) {
      bf16x8 af[4], bfr[4];
#pragma unroll
      for (int mt = 0; mt < 4; ++mt) {
        int r2 = qm + (mt << 4) + rl;
        int c = (kk << 2) + kg;
        af[mt] = *((const bf16x8*)As + ((r2 << 3) | (c ^ (r2 & 7))));
      }
#pragma unroll
      for (int nt = 0; nt < 4; ++nt) {
        int r2 = qn + (nt << 4) + rl;
        int c = (kk << 2) + kg;
        bfr[nt] = *((const bf16x8*)Bs + ((r2 << 3) | (c ^ (r2 & 7))));
      }
#pragma unroll
      for (int mt = 0; mt < 4; ++mt)
#pragma unroll
        for (int nt = 0; nt < 4; ++nt)
          acc[mt][nt] = __builtin_amdgcn_mfma_f32_16x16x32_bf16(
              af[mt], bfr[nt], acc[mt][nt], 0, 0, 0);
    }
    __syncthreads();
  }
#pragma unroll
  for (int nt = 0; nt < 4; ++nt) {
    int colv = n0 + qn + (nt << 4) + rl;
    if (colv < nvmax) {
#pragma unroll
      for (int mt = 0; mt < 4; ++mt)
#pragma unroll
        for (int r = 0; r < 4; ++r) {
          int m = m0 + qm + (mt << 4) + (kg << 2) + r;
          if (MODE == 0) {
            int b = m & 63, t = m >> 6;
            Cf[(size_t)((b << 6) + t) * NV + colv] = acc[mt][nt][r] + bias[colv];
          } else {
            Ch[(size_t)m * NH + colv] = F2B(acc[mt][nt][r]);
          }
        }
    }
  }
}

// ---------------------------------------------------------------------------
// Pipelined skinny GEMM + fused LSTM cell. Grid 256 = dir(2) x gi(128).
// Block: M=64 (batch), N=16 permuted gate cols, K=2048 = x(1536)||h_dir(512).
// BK=128, 3-deep LDS buffers, counted vmcnt, raw barriers, cell epilogue.
// ---------------------------------------------------------------------------
__global__ __launch_bounds__(256) void gates_v2(
    const short* __restrict__ Xt, const short* __restrict__ hcur,
    const short* __restrict__ Wcomb, const float* __restrict__ bperm,
    const float* __restrict__ cq_old, float* __restrict__ hq_f,
    float* __restrict__ cq_new, short* __restrict__ hnext)
{
  __shared__ char smem[61440];
  const int tid = threadIdx.x, lane = tid & 63, w = tid >> 6;
  const int kg = lane >> 4, rl = lane & 15;
  const int dir = blockIdx.x >> 7, gi = blockIdx.x & 127;
  const int hoff = dir << 9;
  const short* Wbase = Wcomb + (((size_t)(dir << 11) + (gi << 4)) << 11);

  auto stage = [&](int it, int buf) {
    char* dst = smem + buf * 20480;
#pragma unroll
    for (int g = 0; g < 4; ++g) {
      int row = (g << 4) + (w << 2) + kg;
      int c = rl ^ (row & 15);
      int k = (it << 7) + (c << 3);
      const short* src = (k < NEH) ? (Xt + (size_t)row * NEH + k)
                                   : (hcur + (size_t)row * NH + hoff + (k - NEH));
      GLD16(src, dst + (g << 12) + (w << 10));
    }
    {
      int rowB = (w << 2) + kg;
      int cB = rl ^ rowB;
      int kB = (it << 7) + (cB << 3);
      GLD16(Wbase + (size_t)rowB * 2048 + kB, dst + 16384 + (w << 10));
    }
  };

  stage(0, 0); stage(1, 1); stage(2, 2);
  f32x4 acc = {};
  int buf = 0;
  for (int it = 0; it < 16; ++it) {
    if (it < 14)      asm volatile("s_waitcnt vmcnt(10)" ::: "memory");
    else if (it == 14) asm volatile("s_waitcnt vmcnt(5)" ::: "memory");
    else               asm volatile("s_waitcnt vmcnt(0)" ::: "memory");
    __builtin_amdgcn_s_barrier();
    __builtin_amdgcn_sched_barrier(0);
    const short* As = (const short*)(smem + buf * 20480);
    const short* Bs = (const short*)(smem + buf * 20480 + 16384);
    const int rowA = (w << 4) + rl;
#pragma unroll
    for (int kk = 0; kk < 4; ++kk) {
      int chunk = (kk << 2) | kg;
      bf16x8 af = *((const bf16x8*)As + ((rowA << 4) | (chunk ^ (rowA & 15))));
      bf16x8 bf = *((const bf16x8*)Bs + ((rl << 4) | (chunk ^ rl)));
      acc = __builtin_amdgcn_mfma_f32_16x16x32_bf16(af, bf, acc, 0, 0, 0);
    }
    __builtin_amdgcn_sched_barrier(0);
    __builtin_amdgcn_s_barrier();
    if (it + 3 < 16) stage(it + 3, buf);
    buf = (buf == 2) ? 0 : buf + 1;
  }
  // epilogue: all loads drained (vmcnt(0) at it=15), all waves past barrier.
  float* gacc = (float*)smem;                    // [64][17]
#pragma unroll
  for (int r = 0; r < 4; ++r)
    gacc[((w << 4) + (kg << 2) + r) * 17 + rl] = acc[r];
  __syncthreads();
  {
    const int b = tid >> 2, j2 = tid & 3;
    const float* bp = bperm + (dir << 11) + (gi << 4) + (j2 << 2);
    const float* gr = gacc + b * 17 + (j2 << 2);
    float gi_ = gr[0] + bp[0];
    float gf_ = gr[1] + bp[1];
    float gg_ = gr[2] + bp[2];
    float go_ = gr[3] + bp[3];
    const int d = ((gi >> 2) << 4) + (((gi << 2) + j2) & 15);
    const int idx = (b << 10) + hoff + d;
    float c0v = cq_old[idx];
    float si = 1.f / (1.f + __expf(-gi_));
    float sf = 1.f / (1.f + __expf(-gf_));
    float so = 1.f / (1.f + __expf(-go_));
    float tg = ftanh(gg_);
    float c2 = sf * c0v + si * tg;
    float h2 = so * ftanh(c2);
    hq_f[idx] = h2;
    cq_new[idx] = c2;
    hnext[idx] = F2B(h2);
  }
}

// ---------------------------------------------------------------------------
// Pipelined q GEMM: grid 64 blocks, M=64, N=16, K=1024, BK=128, 3-deep.
// ---------------------------------------------------------------------------
__global__ __launch_bounds__(256) void q_mm2(const short* __restrict__ hcur,
                                             const short* __restrict__ Wa_h,
                                             float* __restrict__ q)
{
  __shared__ char smem[61440];
  const int tid = threadIdx.x, lane = tid & 63, w = tid >> 6;
  const int kg = lane >> 4, rl = lane & 15;
  const int n0 = blockIdx.x << 4;
  const short* Wbase = Wa_h + (size_t)n0 * NH;

  auto stage = [&](int it, int buf) {
    char* dst = smem + buf * 20480;
#pragma unroll
    for (int g = 0; g < 4; ++g) {
      int row = (g << 4) + (w << 2) + kg;
      int c = rl ^ (row & 15);
      int k = (it << 7) + (c << 3);
      GLD16(hcur + (size_t)row * NH + k, dst + (g << 12) + (w << 10));
    }
    {
      int rowB = (w << 2) + kg;
      int cB = rl ^ rowB;
      int kB = (it << 7) + (cB << 3);
      GLD16(Wbase + (size_t)rowB * NH + kB, dst + 16384 + (w << 10));
    }
  };

  stage(0, 0); stage(1, 1); stage(2, 2);
  f32x4 acc = {};
  int buf = 0;
  for (int it = 0; it < 8; ++it) {
    if (it < 6)       asm volatile("s_waitcnt vmcnt(10)" ::: "memory");
    else if (it == 6) asm volatile("s_waitcnt vmcnt(5)" ::: "memory");
    else              asm volatile("s_waitcnt vmcnt(0)" ::: "memory");
    __builtin_amdgcn_s_barrier();
    __builtin_amdgcn_sched_barrier(0);
    const short* As = (const short*)(smem + buf * 20480);
    const short* Bs = (const short*)(smem + buf * 20480 + 16384);
    const int rowA = (w << 4) + rl;
#pragma unroll
    for (int kk = 0; kk < 4; ++kk) {
      int chunk = (kk << 2) | kg;
      bf16x8 af = *((const bf16x8*)As + ((rowA << 4) | (chunk ^ (rowA & 15))));
      bf16x8 bf = *((const bf16x8*)Bs + ((rl << 4) | (chunk ^ rl)));
      acc = __builtin_amdgcn_mfma_f32_16x16x32_bf16(af, bf, acc, 0, 0, 0);
    }
    __builtin_amdgcn_sched_barrier(0);
    __builtin_amdgcn_s_barrier();
    if (it + 3 < 8) stage(it + 3, buf);
    buf = (buf == 2) ? 0 : buf + 1;
  }
#pragma unroll
  for (int r = 0; r < 4; ++r)
    q[(size_t)((w << 4) + (kg << 2) + r) * NH + n0 + rl] = acc[r];
}

// --- small kernels ----------------------------------------------------------
__global__ __launch_bounds__(256) void f2b_k(const float* __restrict__ in,
                                             short* __restrict__ out, int n4) {
  int i = blockIdx.x * 256 + threadIdx.x;
  const int stride = gridDim.x * 256;
  for (; i < n4; i += stride) {
    float4 v = ((const float4*)in)[i];
    short4 o;
    o.x = F2B(v.x); o.y = F2B(v.y); o.z = F2B(v.z); o.w = F2B(v.w);
    ((short4*)out)[i] = o;
  }
}

__global__ __launch_bounds__(256) void perm_w(
    const float* __restrict__ Wih_f, const float* __restrict__ Whh_f,
    const float* __restrict__ Wih_b, const float* __restrict__ Whh_b,
    const float* __restrict__ bih_f, const float* __restrict__ bhh_f,
    const float* __restrict__ bih_b, const float* __restrict__ bhh_b,
    short* __restrict__ Wcomb, float* __restrict__ bias_perm)
{
  int i = blockIdx.x * 256 + threadIdx.x;        // [0, 2*2048*512)
  int k4 = i & 511;
  int np = (i >> 9) & 2047;
  int dir = i >> 20;
  int gate = np & 3, dlo = (np >> 2) & 15, dblk = np >> 6;
  int d = (dblk << 4) + dlo;
  int r = (gate << 9) + d;
  int k = k4 << 2;
  const float* Wih = dir ? Wih_b : Wih_f;
  const float* Whh = dir ? Whh_b : Whh_f;
  float4 v = (k < NEH) ? *(const float4*)(Wih + (size_t)r * NEH + k)
                       : *(const float4*)(Whh + (size_t)r * ND + (k - NEH));
  short4 o;
  o.x = F2B(v.x); o.y = F2B(v.y); o.z = F2B(v.z); o.w = F2B(v.w);
  *(short4*)(Wcomb + ((size_t)((dir << 11) + np) << 11) + k) = o;
  if (k4 == 0) {
    const float* bi = dir ? bih_b : bih_f;
    const float* bh = dir ? bhh_b : bhh_f;
    bias_perm[(dir << 11) + np] = bi[r] + bh[r];
  }
}

__global__ __launch_bounds__(256) void emb_fill(
    const float* __restrict__ emb, const int* __restrict__ target,
    const int* __restrict__ sos, short* __restrict__ Xbuf)
{
  int idx = blockIdx.x * 256 + threadIdx.x;      // [0, 64*64*128)
  int t = idx >> 13;
  int r = idx & 8191;
  int b = r >> 7, e4 = r & 127;
  int tok = (t == 0) ? sos[0] : target[b * NT + t - 1];
  float4 v = *(const float4*)(emb + (size_t)tok * NE + (e4 << 2));
  short4 o;
  o.x = F2B(v.x); o.y = F2B(v.y); o.z = F2B(v.z); o.w = F2B(v.w);
  *(short4*)(Xbuf + (size_t)(t * NB + b) * NEH + (e4 << 2)) = o;
}

__global__ __launch_bounds__(256) void init_state(
    const float* __restrict__ h0, const float* __restrict__ c0,
    float* __restrict__ hq, float* __restrict__ cq, short* __restrict__ H0) {
  int idx = blockIdx.x * 256 + threadIdx.x;
  int b = idx >> 10, dir = (idx >> 9) & 1, d = idx & 511;
  int src = dir * NB * ND + (b << 9) + d;
  float h = h0[src];
  hq[idx] = h;
  cq[idx] = c0[src];
  H0[idx] = F2B(h);
}

__global__ __launch_bounds__(256) void final_state(
    const float* __restrict__ hq, const float* __restrict__ cq,
    float* __restrict__ out_h, float* __restrict__ out_c) {
  int idx = blockIdx.x * 256 + threadIdx.x;
  int dir = idx >> 15, r = idx & 32767, b = r >> 9, d = r & 511;
  int src = b * NH + dir * ND + d;
  out_h[idx] = hq[src];
  out_c[idx] = cq[src];
}

// one wave per (b,s); q[b] staged in LDS once per block (4 s per block)
// grid MUST be NB*NS/4 = 4096 blocks (b = blockIdx.x>>6).
__global__ __launch_bounds__(256) void attn_score(
    const float* __restrict__ q, const short* __restrict__ Uk,
    const float* __restrict__ Va, const unsigned char* __restrict__ mask,
    float* __restrict__ sc) {
  __shared__ float qs[NH];
  const int b = blockIdx.x >> 6;
  {
    int t4 = threadIdx.x << 2;
    *(float4*)(qs + t4) = *(const float4*)(q + (size_t)b * NH + t4);
  }
  __syncthreads();
  const int lane = threadIdx.x & 63, wid = threadIdx.x >> 6;
  const int bs = (blockIdx.x << 2) + wid;
  const short* ukp = Uk + (size_t)bs * NH;
  float acc = 0.f;
#pragma unroll
  for (int i = 0; i < 2; ++i) {
    int h = (i << 9) + (lane << 3);
    bf16x8 uv = *(const bf16x8*)(ukp + h);
    float4 q0 = *(const float4*)(qs + h);
    float4 q1 = *(const float4*)(qs + h + 4);
    float4 v0 = *(const float4*)(Va + h);
    float4 v1 = *(const float4*)(Va + h + 4);
    acc += v0.x * ftanh(q0.x + B2F(uv[0]));
    acc += v0.y * ftanh(q0.y + B2F(uv[1]));
    acc += v0.z * ftanh(q0.z + B2F(uv[2]));
    acc += v0.w * ftanh(q0.w + B2F(uv[3]));
    acc += v1.x * ftanh(q1.x + B2F(uv[4]));
    acc += v1.y * ftanh(q1.y + B2F(uv[5]));
    acc += v1.z * ftanh(q1.z + B2F(uv[6]));
    acc += v1.w * ftanh(q1.w + B2F(uv[7]));
  }
#pragma unroll
  for (int o = 32; o; o >>= 1) acc += __shfl_down(acc, o);
  if (lane == 0) sc[bs] = mask[bs] ? -__builtin_inff() : acc;
}

// 256 blocks: (b, h-quarter) softmax + ctx -> Xt[:, E:E+H]
__global__ __launch_bounds__(256) void ctx_soft(
    const float* __restrict__ sc, const float* __restrict__ enc_f,
    const short* __restrict__ enc_h, int use_h,
    short* __restrict__ Xt, float* __restrict__ attn_out, int t) {
  const int tid = threadIdx.x;
  const int b = blockIdx.x >> 2, qh = blockIdx.x & 3;
  __shared__ float red[4];
  __shared__ float ws[NS];
  __shared__ float4 red4[4][64];
  float v = sc[b * NS + tid];
  float m = v;
#pragma unroll
  for (int o = 32; o; o >>= 1) m = fmaxf(m, __shfl_down(m, o));
  if ((tid & 63) == 0) red[tid >> 6] = m;
  __syncthreads();
  m = fmaxf(fmaxf(red[0], red[1]), fmaxf(red[2], red[3]));
  float e = __expf(v - m);
  float su = e;
#pragma unroll
  for (int o = 32; o; o >>= 1) su += __shfl_down(su, o);
  __syncthreads();
  if ((tid & 63) == 0) red[tid >> 6] = su;
  __syncthreads();
  su = red[0] + red[1] + red[2] + red[3];
  float wgt = e / su;
  ws[tid] = wgt;
  if (qh == 0) attn_out[((size_t)b * NT + t) * NS + tid] = wgt;
  __syncthreads();
  const int w = tid >> 6, l = tid & 63;
  const int h = (qh << 8) + (l << 2);
  const int s0 = w << 6;
  float4 a = make_float4(0.f, 0.f, 0.f, 0.f);
  if (use_h) {
    const short* ep = enc_h + ((size_t)b * NS + s0) * NH + h;
    for (int s = 0; s < 64; ++s) {
      short4 vv = *(const short4*)(ep + (size_t)s * NH);
      float wv = ws[s0 + s];
      a.x += wv * B2F(vv.x); a.y += wv * B2F(vv.y);
      a.z += wv * B2F(vv.z); a.w += wv * B2F(vv.w);
    }
  } else {
    const float* ep = enc_f + ((size_t)b * NS + s0) * NH + h;
    for (int s = 0; s < 64; ++s) {
      float4 vv = *(const float4*)(ep + (size_t)s * NH);
      float wv = ws[s0 + s];
      a.x += wv * vv.x; a.y += wv * vv.y; a.z += wv * vv.z; a.w += wv * vv.w;
    }
  }
  red4[w][l] = a;
  __syncthreads();
  if (tid < 64) {
    float4 r0 = red4[0][tid], r1 = red4[1][tid], r2 = red4[2][tid],
           r3 = red4[3][tid];
    short4 o;
    o.x = F2B(r0.x + r1.x + r2.x + r3.x);
    o.y = F2B(r0.y + r1.y + r2.y + r3.y);
    o.z = F2B(r0.z + r1.z + r2.z + r3.z);
    o.w = F2B(r0.w + r1.w + r2.w + r3.w);
    *(short4*)(Xt + (size_t)b * NEH + NE + (qh << 8) + (tid << 2)) = o;
  }
}

// ---------------------------------------------------------------------------
extern "C" void kernel_launch(void* const* d_in, const int* in_sizes, int n_in,
                              void* d_out, int out_size, void* d_ws, size_t ws_size,
                              hipStream_t stream)
{
  const float* enc    = (const float*)d_in[0];
  const float* h0     = (const float*)d_in[1];
  const float* c0     = (const float*)d_in[2];
  const int*   target = (const int*)d_in[3];
  const unsigned char* mask = (const unsigned char*)d_in[4];
  const int*   sos    = (const int*)d_in[5];
  const float* emb    = (const float*)d_in[6];
  const float* Wa     = (const float*)d_in[7];
  const float* Ua     = (const float*)d_in[8];
  const float* Va     = (const float*)d_in[9];
  const float* out_W  = (const float*)d_in[10];
  const float* out_b  = (const float*)d_in[11];
  const float* Wih_f  = (const float*)d_in[12];
  const float* Whh_f  = (const float*)d_in[13];
  const float* bih_f  = (const float*)d_in[14];
  const float* bhh_f  = (const float*)d_in[15];
  const float* Wih_b  = (const float*)d_in[16];
  const float* Whh_b  = (const float*)d_in[17];
  const float* bih_b  = (const float*)d_in[18];
  const float* bhh_b  = (const float*)d_in[19];

  float* out_dec  = (float*)d_out;                       // [B][T][V]
  float* out_h    = out_dec + (size_t)NB * NT * NV;      // [2][B][D]
  float* out_c    = out_h + 2 * NB * ND;                 // [2][B][D]
  float* out_attn = out_c + 2 * NB * ND;                 // [B][T][S]

  char* base = (char*)d_ws;
  size_t off = 0;
  auto alloc = [&](size_t bytes) -> char* {
    char* p = base + off;
    off += (bytes + 255) & ~(size_t)255;
    return p;
  };
  short* Uk_h  = (short*)alloc((size_t)NB * NS * NH * 2);     // 33.5 MB
  short* ow_h  = (short*)alloc((size_t)NV * NH * 2);          // 20.5 MB
  short* Ua_h  = (short*)alloc((size_t)NH * NH * 2);
  short* Wa_h  = (short*)alloc((size_t)NH * NH * 2);
  short* Wcomb = (short*)alloc((size_t)2 * 2048 * 2048 * 2);  // 16.8 MB
  float* bperm = (float*)alloc((size_t)2 * 2048 * 4);
  float* q     = (float*)alloc((size_t)NB * NH * 4);
  float* sc    = (float*)alloc((size_t)NB * NS * 4);
  short* Xbuf  = (short*)alloc((size_t)NT * NB * NEH * 2);    // 12.6 MB
  float* hq    = (float*)alloc((size_t)NB * NH * 4);
  float* cq    = (float*)alloc((size_t)2 * NB * NH * 4);
  short* Hbuf  = (short*)alloc((size_t)(NT + 1) * NB * NH * 2); // 8.5 MB
  short* enc_h = nullptr;
  int use_h = 0;
  if (off + (size_t)NB * NS * NH * 2 <= ws_size) {
    enc_h = (short*)alloc((size_t)NB * NS * NH * 2);          // 33.5 MB
    use_h = 1;
  }
  if (off > ws_size) return;  // insufficient scratch

  // ---- setup ----
  f2b_k<<<dim3(2048), dim3(256), 0, stream>>>(out_W, ow_h, NV * NH / 4);
  f2b_k<<<dim3(1024), dim3(256), 0, stream>>>(Ua, Ua_h, NH * NH / 4);
  f2b_k<<<dim3(1024), dim3(256), 0, stream>>>(Wa, Wa_h, NH * NH / 4);
  perm_w<<<dim3(8192), dim3(256), 0, stream>>>(Wih_f, Whh_f, Wih_b, Whh_b,
                                               bih_f, bhh_f, bih_b, bhh_b,
                                               Wcomb, bperm);
  emb_fill<<<dim3(2048), dim3(256), 0, stream>>>(emb, target, sos, Xbuf);
  init_state<<<dim3(256), dim3(256), 0, stream>>>(h0, c0, hq, cq, Hbuf);
  if (use_h) {
    f2b_k<<<dim3(2048), dim3(256), 0, stream>>>(enc, enc_h, NB * NS * NH / 4);
    mm128<1><<<dim3(8, 128), dim3(256), 0, stream>>>(enc_h, Ua_h, NH, nullptr,
                                                     nullptr, Uk_h);
  } else {
    uk_mm_f32<<<dim3(16, 256), dim3(256), 0, stream>>>(enc, Ua_h, Uk_h);
  }

  // ---- recurrent loop ----
  for (int t = 0; t < NT; ++t) {
    const short* hcur = Hbuf + (size_t)t * NB * NH;
    short* hnext = Hbuf + (size_t)(t + 1) * NB * NH;
    float* cq_cur = cq + (t & 1) * (NB * NH);
    float* cq_nxt = cq + ((t & 1) ^ 1) * (NB * NH);
    short* Xt = Xbuf + (size_t)t * NB * NEH;

    q_mm2<<<dim3(64), dim3(256), 0, stream>>>(hcur, Wa_h, q);
    attn_score<<<dim3(4096), dim3(256), 0, stream>>>(q, Uk_h, Va, mask, sc);
    ctx_soft<<<dim3(256), dim3(256), 0, stream>>>(sc, enc, enc_h, use_h,
                                                  Xt, out_attn, t);
    gates_v2<<<dim3(256), dim3(256), 0, stream>>>(Xt, hcur, Wcomb, bperm,
                                                  cq_cur, hq, cq_nxt, hnext);
  }

  // ---- batched vocab projection over all steps ----
  mm128<0><<<dim3(79, 32), dim3(256), 0, stream>>>(Hbuf + NB * NH, ow_h, NV,
                                                   out_b, out_dec, nullptr);
  final_state<<<dim3(256), dim3(256), 0, stream>>>(hq, cq, out_h, out_c);
}